// Round 6
// baseline (16.321 us; speedup 1.0000x reference)
//
#include <hip/hip_runtime.h>

// Problem constants (match reference)
#define BATCH     16
#define SEQ_N     1024
#define EMBED_DIM 256

typedef float f32x4 __attribute__((ext_vector_type(4)));

// out[b][d][n] = embedding[seq[b][n]][d]
//
// Transpose-free decomposition: lane l <-> n = n0 + l. Lane l gathers its own
// row slice emb[seq[b][n]][d0..d0+15] (4x dwordx4, per-lane sequential 64B).
// For each d, the wave's 64 lanes hold out[b][d][n0..n0+63] in lane order ->
// one perfectly-coalesced 256B NT store per d. No LDS, no barrier.
//
// wave = (b, n-chunk of 64, d-chunk of 16); block = 4 waves = 4 consecutive
// d-chunks. grid = 16 b * 16 nchunk * 4 dgroup = 1024 blocks, 16 waves/CU.
__global__ __launch_bounds__(256) void
embed_gather_direct(const int* __restrict__ seq,
                    const float* __restrict__ emb,
                    float* __restrict__ out) {
    const int wave = threadIdx.x >> 6;
    const int lane = threadIdx.x & 63;

    const int dgroup = blockIdx.x & 3;          // 4 d-groups of 64
    const int nchunk = (blockIdx.x >> 2) & 15;  // 16 n-chunks of 64
    const int b      = blockIdx.x >> 6;         // 16 batches

    const int n  = (nchunk << 6) + lane;
    const int d0 = (dgroup << 6) + (wave << 4); // 16 d per wave

    const int row = seq[b * SEQ_N + n];         // 256B coalesced per wave

    const f32x4* src =
        reinterpret_cast<const f32x4*>(emb + (size_t)row * EMBED_DIM + d0);
    const f32x4 v0 = src[0];
    const f32x4 v1 = src[1];
    const f32x4 v2 = src[2];
    const f32x4 v3 = src[3];

    float* o = out + ((size_t)b * EMBED_DIM + d0) * SEQ_N + n;
    // 16 NT scalar stores; each wave-instr covers a contiguous, line-aligned
    // 256B span of out[b][d][n0..n0+63]. NT: write-once output, avoid RFO.
    __builtin_nontemporal_store(v0.x, o + 0  * SEQ_N);
    __builtin_nontemporal_store(v0.y, o + 1  * SEQ_N);
    __builtin_nontemporal_store(v0.z, o + 2  * SEQ_N);
    __builtin_nontemporal_store(v0.w, o + 3  * SEQ_N);
    __builtin_nontemporal_store(v1.x, o + 4  * SEQ_N);
    __builtin_nontemporal_store(v1.y, o + 5  * SEQ_N);
    __builtin_nontemporal_store(v1.z, o + 6  * SEQ_N);
    __builtin_nontemporal_store(v1.w, o + 7  * SEQ_N);
    __builtin_nontemporal_store(v2.x, o + 8  * SEQ_N);
    __builtin_nontemporal_store(v2.y, o + 9  * SEQ_N);
    __builtin_nontemporal_store(v2.z, o + 10 * SEQ_N);
    __builtin_nontemporal_store(v2.w, o + 11 * SEQ_N);
    __builtin_nontemporal_store(v3.x, o + 12 * SEQ_N);
    __builtin_nontemporal_store(v3.y, o + 13 * SEQ_N);
    __builtin_nontemporal_store(v3.z, o + 14 * SEQ_N);
    __builtin_nontemporal_store(v3.w, o + 15 * SEQ_N);
}

extern "C" void kernel_launch(void* const* d_in, const int* in_sizes, int n_in,
                              void* d_out, int out_size, void* d_ws, size_t ws_size,
                              hipStream_t stream) {
    const int*   seq = (const int*)d_in[0];
    const float* emb = (const float*)d_in[1];
    float*       out = (float*)d_out;

    const int grid = BATCH * (SEQ_N / 64) * (EMBED_DIM / 64);  // 1024
    embed_gather_direct<<<grid, 256, 0, stream>>>(seq, emb, out);
}